// Round 1
// baseline (298.202 us; speedup 1.0000x reference)
//
#include <hip/hip_runtime.h>
#include <cstdint>
#include <cstddef>

typedef __bf16 bf16_t;
typedef bf16_t bf16x8 __attribute__((ext_vector_type(8)));
typedef bf16_t bf16x4 __attribute__((ext_vector_type(4)));
typedef float  f32x4  __attribute__((ext_vector_type(4)));

#define MFMA16(a, b, c) __builtin_amdgcn_mfma_f32_16x16x32_bf16((a), (b), (c), 0, 0, 0)

static constexpr int Bb = 2, Ss = 2048, Hh = 16, Dd = 128, DH = 2048;
static constexpr float QSCALE = 0.08838834764831845f; // 1/sqrt(128)

// ---------------- prep: f32 -> bf16 convert ----------------
__global__ void k_cvt_x(const float* __restrict__ in, bf16_t* __restrict__ out) {
    int i = (blockIdx.x * 256 + threadIdx.x) * 4;
    float4 v = *reinterpret_cast<const float4*>(in + i);
    bf16x4 o;
    o[0] = (bf16_t)v.x; o[1] = (bf16_t)v.y; o[2] = (bf16_t)v.z; o[3] = (bf16_t)v.w;
    *reinterpret_cast<bf16x4*>(out + i) = o;
}

// ---------------- prep: transpose f32 (R x C) -> bf16 (C x R) ----------------
__global__ void k_transpose_bf16(const float* __restrict__ in, bf16_t* __restrict__ out,
                                 int R, int C) {
    __shared__ float t[32][33];
    int tx = threadIdx.x, ty = threadIdx.y;          // 32 x 8
    int c0 = blockIdx.x * 32, r0 = blockIdx.y * 32;
#pragma unroll
    for (int i = 0; i < 4; i++)
        t[ty + i * 8][tx] = in[(size_t)(r0 + ty + i * 8) * C + c0 + tx];
    __syncthreads();
#pragma unroll
    for (int i = 0; i < 4; i++)
        out[(size_t)(c0 + ty + i * 8) * R + r0 + tx] = (bf16_t)t[tx][ty + i * 8];
}

// ---------------- QKV projection GEMM ----------------
// x_bf16 (4096 x 128) @ W (128 x 2048) + b  -> Q/K (B,H,S,D) bf16, V (B,H,D,S) bf16
// grid (32, 16, 3): x = m-tile (128 rows), y = head (128 cols), z = which matrix
__global__ __launch_bounds__(256) void k_qkv(
    const bf16_t* __restrict__ xb, const bf16_t* __restrict__ Wt,
    const float* __restrict__ bq, const float* __restrict__ bk, const float* __restrict__ bv,
    bf16_t* __restrict__ Qw, bf16_t* __restrict__ Kw, bf16_t* __restrict__ Vw) {
    __shared__ bf16_t smem[18432];                       // 36864 B
    bf16_t (*As)[72] = reinterpret_cast<bf16_t(*)[72]>(smem);
    bf16_t (*Bs)[72] = reinterpret_cast<bf16_t(*)[72]>(smem + 9216);

    const int tid = threadIdx.x;
    const int w = tid >> 6, lane = tid & 63, c = lane & 15, g = lane >> 4;
    const int m0 = blockIdx.x * 128, n0g = blockIdx.y * 128, z = blockIdx.z;
    const bf16_t* Wz = Wt + (size_t)z * DH * Dd;
    const int wm = w * 32;

    f32x4 acc[2][8];
#pragma unroll
    for (int a = 0; a < 2; a++)
#pragma unroll
        for (int b = 0; b < 8; b++) acc[a][b] = f32x4{0.f, 0.f, 0.f, 0.f};

    for (int kt = 0; kt < 128; kt += 64) {
        __syncthreads();
#pragma unroll
        for (int i = 0; i < 4; i++) {
            int e = tid + i * 256; int row = e >> 3, col = (e & 7) * 8;
            *reinterpret_cast<uint4*>(&As[row][col]) =
                *reinterpret_cast<const uint4*>(&xb[(size_t)(m0 + row) * 128 + kt + col]);
        }
#pragma unroll
        for (int i = 0; i < 4; i++) {
            int e = tid + i * 256; int row = e >> 3, col = (e & 7) * 8;
            *reinterpret_cast<uint4*>(&Bs[row][col]) =
                *reinterpret_cast<const uint4*>(&Wz[(size_t)(n0g + row) * 128 + kt + col]);
        }
        __syncthreads();
#pragma unroll
        for (int kb = 0; kb < 2; kb++) {
            bf16x8 af[2];
#pragma unroll
            for (int mb = 0; mb < 2; mb++)
                af[mb] = *reinterpret_cast<const bf16x8*>(&As[wm + mb * 16 + c][kb * 32 + g * 8]);
#pragma unroll
            for (int nb = 0; nb < 8; nb++) {
                bf16x8 bfr = *reinterpret_cast<const bf16x8*>(&Bs[nb * 16 + c][kb * 32 + g * 8]);
                acc[0][nb] = MFMA16(af[0], bfr, acc[0][nb]);
                acc[1][nb] = MFMA16(af[1], bfr, acc[1][nb]);
            }
        }
    }

    // epilogue: +bias (scale Q by 1/sqrt(D)), stage through LDS for coalesced writes
    const float* bias = (z == 0) ? bq : (z == 1) ? bk : bv;
    const float sc = (z == 0) ? QSCALE : 1.0f;
    const int cstride = (z == 2) ? 131 : 136;            // V path avoids transpose-read conflicts
    __syncthreads();
#pragma unroll
    for (int mb = 0; mb < 2; mb++)
#pragma unroll
        for (int nb = 0; nb < 8; nb++) {
            float bs = bias[n0g + nb * 16 + c];
#pragma unroll
            for (int r = 0; r < 4; r++) {
                int row = wm + mb * 16 + g * 4 + r;
                int col = nb * 16 + c;
                smem[row * cstride + col] = (bf16_t)((acc[mb][nb][r] + bs) * sc);
            }
        }
    __syncthreads();
    const int h = blockIdx.y;
    if (z <= 1) {   // Q/K -> (B,H,S,D)
        bf16_t* O = z ? Kw : Qw;
#pragma unroll
        for (int i = 0; i < 8; i++) {
            int e = tid + i * 256; int row = e >> 4, col = (e & 15) * 8;
            int sg = m0 + row, b = sg >> 11, s2 = sg & 2047;
            *reinterpret_cast<uint4*>(&O[(((size_t)(b * Hh + h)) * Ss + s2) * Dd + col]) =
                *reinterpret_cast<const uint4*>(&smem[row * 136 + col]);
        }
    } else {        // V -> (B,H,D,S)  (transposed out of LDS, packed 2-at-a-time)
        int b = m0 >> 11; int sbase = m0 & 2047;
        const unsigned short* cs16 = reinterpret_cast<const unsigned short*>(smem);
#pragma unroll
        for (int i = 0; i < 32; i++) {
            int e = tid + i * 256; int d = e >> 6, sl2 = (e & 63) * 2;
            unsigned int lo = cs16[sl2 * 131 + d], hi = cs16[(sl2 + 1) * 131 + d];
            unsigned int pk = lo | (hi << 16);
            *reinterpret_cast<unsigned int*>(
                &Vw[(((size_t)(b * Hh + h)) * Dd + d) * Ss + sbase + sl2]) = pk;
        }
    }
}

// ---------------- flash attention ----------------
// grid (32, 32): x = q-tile (64 rows), y = b*H+h. 4 waves x 16 q-rows.
__global__ __launch_bounds__(256) void k_attn(
    const bf16_t* __restrict__ Qw, const bf16_t* __restrict__ Kw,
    const bf16_t* __restrict__ Vw, bf16_t* __restrict__ AO) {
    __shared__ bf16_t Kt[64][136];     // K tile  [kv][d]
    __shared__ bf16_t Vt[128][72];     // V^T tile [d][kv]
    __shared__ bf16_t Pb[4][16][72];   // per-wave P buffer [qrow][kv]

    const int tid = threadIdx.x;
    const int w = tid >> 6, lane = tid & 63, c = lane & 15, g = lane >> 4;
    const int bh = blockIdx.y, q0 = blockIdx.x * 64;
    const bf16_t* Qb = Qw + (size_t)bh * Ss * Dd;
    const bf16_t* Kb = Kw + (size_t)bh * Ss * Dd;
    const bf16_t* Vb = Vw + (size_t)bh * Dd * Ss;

    bf16x8 qf[4];
    const int qr = q0 + w * 16 + c;
#pragma unroll
    for (int kb = 0; kb < 4; kb++)
        qf[kb] = *reinterpret_cast<const bf16x8*>(&Qb[(size_t)qr * Dd + kb * 32 + g * 8]);

    f32x4 ao[8];
#pragma unroll
    for (int i = 0; i < 8; i++) ao[i] = f32x4{0.f, 0.f, 0.f, 0.f};
    float m_run[4] = {-1e30f, -1e30f, -1e30f, -1e30f};
    float l_run[4] = {0.f, 0.f, 0.f, 0.f};

    for (int kv0 = 0; kv0 < Ss; kv0 += 64) {
        __syncthreads();
#pragma unroll
        for (int i = 0; i < 4; i++) {   // stage K: 64 x 128
            int e = tid + i * 256; int row = e >> 4, col = (e & 15) * 8;
            *reinterpret_cast<uint4*>(&Kt[row][col]) =
                *reinterpret_cast<const uint4*>(&Kb[(size_t)(kv0 + row) * Dd + col]);
        }
#pragma unroll
        for (int i = 0; i < 4; i++) {   // stage V^T: 128 x 64
            int e = tid + i * 256; int row = e >> 3, col = (e & 7) * 8;
            *reinterpret_cast<uint4*>(&Vt[row][col]) =
                *reinterpret_cast<const uint4*>(&Vb[(size_t)row * Ss + kv0 + col]);
        }
        __syncthreads();

        // S = Q K^T (rows = q, cols = kv)
        f32x4 sacc[4];
#pragma unroll
        for (int nb = 0; nb < 4; nb++) sacc[nb] = f32x4{0.f, 0.f, 0.f, 0.f};
#pragma unroll
        for (int kb = 0; kb < 4; kb++)
#pragma unroll
            for (int nb = 0; nb < 4; nb++) {
                bf16x8 kf = *reinterpret_cast<const bf16x8*>(&Kt[nb * 16 + c][kb * 32 + g * 8]);
                sacc[nb] = MFMA16(qf[kb], kf, sacc[nb]);
            }

        // online softmax, wave-parallel (16-lane row groups)
#pragma unroll
        for (int r = 0; r < 4; r++) {
            float mx = fmaxf(fmaxf(sacc[0][r], sacc[1][r]), fmaxf(sacc[2][r], sacc[3][r]));
#pragma unroll
            for (int off = 1; off < 16; off <<= 1) mx = fmaxf(mx, __shfl_xor(mx, off));
            float mn = fmaxf(m_run[r], mx);
            float scale = __expf(m_run[r] - mn);
            m_run[r] = mn;
            float p0 = __expf(sacc[0][r] - mn), p1 = __expf(sacc[1][r] - mn);
            float p2 = __expf(sacc[2][r] - mn), p3 = __expf(sacc[3][r] - mn);
            float rs = p0 + p1 + p2 + p3;
#pragma unroll
            for (int off = 1; off < 16; off <<= 1) rs += __shfl_xor(rs, off);
            l_run[r] = l_run[r] * scale + rs;
#pragma unroll
            for (int i = 0; i < 8; i++) ao[i][r] *= scale;
            int prow = g * 4 + r;
            Pb[w][prow][ 0 + c] = (bf16_t)p0;
            Pb[w][prow][16 + c] = (bf16_t)p1;
            Pb[w][prow][32 + c] = (bf16_t)p2;
            Pb[w][prow][48 + c] = (bf16_t)p3;
        }
        asm volatile("s_waitcnt lgkmcnt(0)" ::: "memory");  // Pb is wave-private: fence, no barrier

        // O += P V
        bf16x8 pf[2];
#pragma unroll
        for (int kb2 = 0; kb2 < 2; kb2++)
            pf[kb2] = *reinterpret_cast<const bf16x8*>(&Pb[w][c][kb2 * 32 + g * 8]);
#pragma unroll
        for (int db = 0; db < 8; db++)
#pragma unroll
            for (int kb2 = 0; kb2 < 2; kb2++) {
                bf16x8 vf = *reinterpret_cast<const bf16x8*>(&Vt[db * 16 + c][kb2 * 32 + g * 8]);
                ao[db] = MFMA16(pf[kb2], vf, ao[db]);
            }
    }

    // epilogue: normalize, stage in LDS, coalesced write to (B,S,H*D)
    __syncthreads();
#pragma unroll
    for (int r = 0; r < 4; r++) {
        float inv = 1.0f / l_run[r];
#pragma unroll
        for (int db = 0; db < 8; db++)
            Kt[w * 16 + g * 4 + r][db * 16 + c] = (bf16_t)(ao[db][r] * inv);
    }
    __syncthreads();
    const int b = bh >> 4, h = bh & 15;
#pragma unroll
    for (int i = 0; i < 4; i++) {
        int e = tid + i * 256; int row = e >> 4, col = (e & 15) * 8;
        *reinterpret_cast<uint4*>(&AO[((size_t)(b * Ss + q0 + row)) * DH + h * Dd + col]) =
            *reinterpret_cast<const uint4*>(&Kt[row][col]);
    }
}

// ---------------- output projection ----------------
// AO (4096 x 2048) bf16 @ Wo (2048 x 128) + bo -> out f32 (4096 x 128)
__global__ __launch_bounds__(256) void k_outproj(
    const bf16_t* __restrict__ A, const bf16_t* __restrict__ Wot,
    const float* __restrict__ bo, float* __restrict__ out) {
    __shared__ bf16_t As[64][72];
    __shared__ bf16_t Bs[128][72];
    const int tid = threadIdx.x;
    const int w = tid >> 6, lane = tid & 63, c = lane & 15, g = lane >> 4;
    const int m0 = blockIdx.x * 64;

    f32x4 acc[8];
#pragma unroll
    for (int i = 0; i < 8; i++) acc[i] = f32x4{0.f, 0.f, 0.f, 0.f};

    for (int kt = 0; kt < DH; kt += 64) {
        __syncthreads();
#pragma unroll
        for (int i = 0; i < 2; i++) {
            int e = tid + i * 256; int row = e >> 3, col = (e & 7) * 8;
            *reinterpret_cast<uint4*>(&As[row][col]) =
                *reinterpret_cast<const uint4*>(&A[(size_t)(m0 + row) * DH + kt + col]);
        }
#pragma unroll
        for (int i = 0; i < 4; i++) {
            int e = tid + i * 256; int row = e >> 3, col = (e & 7) * 8;
            *reinterpret_cast<uint4*>(&Bs[row][col]) =
                *reinterpret_cast<const uint4*>(&Wot[(size_t)row * DH + kt + col]);
        }
        __syncthreads();
#pragma unroll
        for (int kb = 0; kb < 2; kb++) {
            bf16x8 af = *reinterpret_cast<const bf16x8*>(&As[w * 16 + c][kb * 32 + g * 8]);
#pragma unroll
            for (int nb = 0; nb < 8; nb++) {
                bf16x8 bfr = *reinterpret_cast<const bf16x8*>(&Bs[nb * 16 + c][kb * 32 + g * 8]);
                acc[nb] = MFMA16(af, bfr, acc[nb]);
            }
        }
    }
#pragma unroll
    for (int nb = 0; nb < 8; nb++) {
        float bs = bo[nb * 16 + c];
#pragma unroll
        for (int r = 0; r < 4; r++) {
            int row = m0 + w * 16 + g * 4 + r;
            out[(size_t)row * Dd + nb * 16 + c] = acc[nb][r] + bs;
        }
    }
}

// ---------------- launcher ----------------
extern "C" void kernel_launch(void* const* d_in, const int* in_sizes, int n_in,
                              void* d_out, int out_size, void* d_ws, size_t ws_size,
                              hipStream_t stream) {
    const float* x  = (const float*)d_in[0];
    const float* Wq = (const float*)d_in[1];
    const float* bq = (const float*)d_in[2];
    const float* Wk = (const float*)d_in[3];
    const float* bk = (const float*)d_in[4];
    const float* Wv = (const float*)d_in[5];
    const float* bv = (const float*)d_in[6];
    const float* Wo = (const float*)d_in[7];
    const float* bo = (const float*)d_in[8];
    float* out = (float*)d_out;

    char* ws = (char*)d_ws;
    bf16_t* xb  = (bf16_t*)(ws);                                  // 1 MB
    bf16_t* Wt  = (bf16_t*)(ws + 1048576);                        // 1.5 MB (Wq^T,Wk^T,Wv^T)
    bf16_t* Wot = (bf16_t*)(ws + 2621440);                        // 0.5 MB
    bf16_t* Qw  = (bf16_t*)(ws + 3145728);                        // 16 MB
    bf16_t* Kw  = (bf16_t*)(ws + 3145728 + 16777216);             // 16 MB
    bf16_t* Vw  = (bf16_t*)(ws + 3145728 + 2 * 16777216);         // 16 MB
    bf16_t* AO  = (bf16_t*)(ws + 3145728 + 3 * 16777216);         // 16 MB

    k_cvt_x<<<512, 256, 0, stream>>>(x, xb);
    k_transpose_bf16<<<dim3(64, 4), dim3(32, 8), 0, stream>>>(Wq, Wt,          128, 2048);
    k_transpose_bf16<<<dim3(64, 4), dim3(32, 8), 0, stream>>>(Wk, Wt + 262144, 128, 2048);
    k_transpose_bf16<<<dim3(64, 4), dim3(32, 8), 0, stream>>>(Wv, Wt + 524288, 128, 2048);
    k_transpose_bf16<<<dim3(4, 64), dim3(32, 8), 0, stream>>>(Wo, Wot,         2048, 128);
    k_qkv<<<dim3(32, 16, 3), 256, 0, stream>>>(xb, Wt, bq, bk, bv, Qw, Kw, Vw);
    k_attn<<<dim3(32, 32), 256, 0, stream>>>(Qw, Kw, Vw, AO);
    k_outproj<<<64, 256, 0, stream>>>(AO, Wot, bo, out);
}

// Round 2
// 211.283 us; speedup vs baseline: 1.4114x; 1.4114x over previous
//
#include <hip/hip_runtime.h>
#include <cstdint>
#include <cstddef>

typedef __bf16 bf16_t;
typedef bf16_t bf16x8 __attribute__((ext_vector_type(8)));
typedef bf16_t bf16x4 __attribute__((ext_vector_type(4)));
typedef float  f32x4  __attribute__((ext_vector_type(4)));

#define MFMA16(a, b, c) __builtin_amdgcn_mfma_f32_16x16x32_bf16((a), (b), (c), 0, 0, 0)

static constexpr int Bb = 2, Ss = 2048, Hh = 16, Dd = 128, DH = 2048;
static constexpr float QSCALE = 0.08838834764831845f; // 1/sqrt(128)

// ---------------- prep: f32 -> bf16 convert ----------------
__global__ void k_cvt_x(const float* __restrict__ in, bf16_t* __restrict__ out) {
    int i = (blockIdx.x * 256 + threadIdx.x) * 4;
    float4 v = *reinterpret_cast<const float4*>(in + i);
    bf16x4 o;
    o[0] = (bf16_t)v.x; o[1] = (bf16_t)v.y; o[2] = (bf16_t)v.z; o[3] = (bf16_t)v.w;
    *reinterpret_cast<bf16x4*>(out + i) = o;
}

// ---------------- prep: transpose f32 (R x C) -> bf16 (C x R) ----------------
__global__ void k_transpose_bf16(const float* __restrict__ in, bf16_t* __restrict__ out,
                                 int R, int C) {
    __shared__ float t[32][33];
    int tx = threadIdx.x, ty = threadIdx.y;          // 32 x 8
    int c0 = blockIdx.x * 32, r0 = blockIdx.y * 32;
#pragma unroll
    for (int i = 0; i < 4; i++)
        t[ty + i * 8][tx] = in[(size_t)(r0 + ty + i * 8) * C + c0 + tx];
    __syncthreads();
#pragma unroll
    for (int i = 0; i < 4; i++)
        out[(size_t)(c0 + ty + i * 8) * R + r0 + tx] = (bf16_t)t[tx][ty + i * 8];
}

// ---------------- QKV projection GEMM ----------------
__global__ __launch_bounds__(256) void k_qkv(
    const bf16_t* __restrict__ xb, const bf16_t* __restrict__ Wt,
    const float* __restrict__ bq, const float* __restrict__ bk, const float* __restrict__ bv,
    bf16_t* __restrict__ Qw, bf16_t* __restrict__ Kw, bf16_t* __restrict__ Vw) {
    __shared__ bf16_t smem[18432];
    bf16_t (*As)[72] = reinterpret_cast<bf16_t(*)[72]>(smem);
    bf16_t (*Bs)[72] = reinterpret_cast<bf16_t(*)[72]>(smem + 9216);

    const int tid = threadIdx.x;
    const int w = tid >> 6, lane = tid & 63, c = lane & 15, g = lane >> 4;
    const int m0 = blockIdx.x * 128, n0g = blockIdx.y * 128, z = blockIdx.z;
    const bf16_t* Wz = Wt + (size_t)z * DH * Dd;
    const int wm = w * 32;

    f32x4 acc[2][8];
#pragma unroll
    for (int a = 0; a < 2; a++)
#pragma unroll
        for (int b = 0; b < 8; b++) acc[a][b] = f32x4{0.f, 0.f, 0.f, 0.f};

    for (int kt = 0; kt < 128; kt += 64) {
        __syncthreads();
#pragma unroll
        for (int i = 0; i < 4; i++) {
            int e = tid + i * 256; int row = e >> 3, col = (e & 7) * 8;
            *reinterpret_cast<uint4*>(&As[row][col]) =
                *reinterpret_cast<const uint4*>(&xb[(size_t)(m0 + row) * 128 + kt + col]);
        }
#pragma unroll
        for (int i = 0; i < 4; i++) {
            int e = tid + i * 256; int row = e >> 3, col = (e & 7) * 8;
            *reinterpret_cast<uint4*>(&Bs[row][col]) =
                *reinterpret_cast<const uint4*>(&Wz[(size_t)(n0g + row) * 128 + kt + col]);
        }
        __syncthreads();
#pragma unroll
        for (int kb = 0; kb < 2; kb++) {
            bf16x8 af[2];
#pragma unroll
            for (int mb = 0; mb < 2; mb++)
                af[mb] = *reinterpret_cast<const bf16x8*>(&As[wm + mb * 16 + c][kb * 32 + g * 8]);
#pragma unroll
            for (int nb = 0; nb < 8; nb++) {
                bf16x8 bfr = *reinterpret_cast<const bf16x8*>(&Bs[nb * 16 + c][kb * 32 + g * 8]);
                acc[0][nb] = MFMA16(af[0], bfr, acc[0][nb]);
                acc[1][nb] = MFMA16(af[1], bfr, acc[1][nb]);
            }
        }
    }

    const float* bias = (z == 0) ? bq : (z == 1) ? bk : bv;
    const float sc = (z == 0) ? QSCALE : 1.0f;
    const int cstride = (z == 2) ? 131 : 136;
    __syncthreads();
#pragma unroll
    for (int mb = 0; mb < 2; mb++)
#pragma unroll
        for (int nb = 0; nb < 8; nb++) {
            float bs = bias[n0g + nb * 16 + c];
#pragma unroll
            for (int r = 0; r < 4; r++) {
                int row = wm + mb * 16 + g * 4 + r;
                int col = nb * 16 + c;
                smem[row * cstride + col] = (bf16_t)((acc[mb][nb][r] + bs) * sc);
            }
        }
    __syncthreads();
    const int h = blockIdx.y;
    if (z <= 1) {
        bf16_t* O = z ? Kw : Qw;
#pragma unroll
        for (int i = 0; i < 8; i++) {
            int e = tid + i * 256; int row = e >> 4, col = (e & 15) * 8;
            int sg = m0 + row, b = sg >> 11, s2 = sg & 2047;
            *reinterpret_cast<uint4*>(&O[(((size_t)(b * Hh + h)) * Ss + s2) * Dd + col]) =
                *reinterpret_cast<const uint4*>(&smem[row * 136 + col]);
        }
    } else {
        int b = m0 >> 11; int sbase = m0 & 2047;
        const unsigned short* cs16 = reinterpret_cast<const unsigned short*>(smem);
#pragma unroll
        for (int i = 0; i < 32; i++) {
            int e = tid + i * 256; int d = e >> 6, sl2 = (e & 63) * 2;
            unsigned int lo = cs16[sl2 * 131 + d], hi = cs16[(sl2 + 1) * 131 + d];
            unsigned int pk = lo | (hi << 16);
            *reinterpret_cast<unsigned int*>(
                &Vw[(((size_t)(b * Hh + h)) * Dd + d) * Ss + sbase + sl2]) = pk;
        }
    }
}

// ---------------- flash attention (swapped QK^T, 8 waves, QBLK=128) ----------------
// grid: 512 blocks x 512 threads. XCD-swizzled decode: each XCD keeps 4 heads' K/V in L2.
__global__ __launch_bounds__(512, 4) void k_attn(
    const bf16_t* __restrict__ Qw, const bf16_t* __restrict__ Kw,
    const bf16_t* __restrict__ Vw, bf16_t* __restrict__ AO) {
    // LDS carve: Kt 64x136 (8704), Vt 128x72 (9216), Pb 8x16x72 (9216) = 27136 elems = 54272 B
    __shared__ bf16_t smem[27136];
    bf16_t (*Kt)[136] = reinterpret_cast<bf16_t(*)[136]>(smem);
    bf16_t (*Vt)[72]  = reinterpret_cast<bf16_t(*)[72]>(smem + 8704);
    bf16_t (*Pb)[72]  = reinterpret_cast<bf16_t(*)[72]>(smem + 17920);  // [8*16][72]

    const int tid = threadIdx.x;
    const int w = tid >> 6, lane = tid & 63, c = lane & 15, g = lane >> 4;

    // bijective XCD swizzle: 512 % 8 == 0
    const int f = blockIdx.x;
    const int wid = (f & 7) * 64 + (f >> 3);
    const int bh = wid >> 4, q0 = (wid & 15) * 128;

    const bf16_t* Qb = Qw + (size_t)bh * Ss * Dd;
    const bf16_t* Kb = Kw + (size_t)bh * Ss * Dd;
    const bf16_t* Vb = Vw + (size_t)bh * Dd * Ss;

    // Q fragments: wave w owns q rows [q0 + w*16, +16); B-frag: col=c -> q, k=g*8+i -> d
    bf16x8 qf[4];
    const int qr = q0 + w * 16 + c;
#pragma unroll
    for (int kb = 0; kb < 4; kb++)
        qf[kb] = *reinterpret_cast<const bf16x8*>(&Qb[(size_t)qr * Dd + kb * 32 + g * 8]);

    f32x4 ao[8];
#pragma unroll
    for (int i = 0; i < 8; i++) ao[i] = f32x4{0.f, 0.f, 0.f, 0.f};
    float m_run = -1e30f, l_run = 0.f;   // per-lane: q-row = c

    for (int kv0 = 0; kv0 < Ss; kv0 += 64) {
        __syncthreads();
#pragma unroll
        for (int i = 0; i < 2; i++) {   // stage K: 64 x 128 (1024 uint4, 512 thr)
            int e = tid + i * 512; int row = e >> 4, col = (e & 15) * 8;
            *reinterpret_cast<uint4*>(&Kt[row][col]) =
                *reinterpret_cast<const uint4*>(&Kb[(size_t)(kv0 + row) * Dd + col]);
        }
#pragma unroll
        for (int i = 0; i < 2; i++) {   // stage V^T: 128 x 64
            int e = tid + i * 512; int row = e >> 3, col = (e & 7) * 8;
            *reinterpret_cast<uint4*>(&Vt[row][col]) =
                *reinterpret_cast<const uint4*>(&Vb[(size_t)row * Ss + kv0 + col]);
        }
        __syncthreads();

        // S^T = K Q^T : C[kv][q], q = c (lane-local row!), kv = nb*16 + g*4 + r
        f32x4 sacc[4];
#pragma unroll
        for (int nb = 0; nb < 4; nb++) sacc[nb] = f32x4{0.f, 0.f, 0.f, 0.f};
        __builtin_amdgcn_s_setprio(1);
#pragma unroll
        for (int kb = 0; kb < 4; kb++)
#pragma unroll
            for (int nb = 0; nb < 4; nb++) {
                bf16x8 kf = *reinterpret_cast<const bf16x8*>(&Kt[nb * 16 + c][kb * 32 + g * 8]);
                sacc[nb] = MFMA16(kf, qf[kb], sacc[nb]);
            }
        __builtin_amdgcn_s_setprio(0);

        // online softmax: lane owns full q-row (16 vals) + 2-shuffle cross-g reduce
        float pm = fmaxf(fmaxf(sacc[0][0], sacc[0][1]), fmaxf(sacc[0][2], sacc[0][3]));
#pragma unroll
        for (int nb = 1; nb < 4; nb++)
#pragma unroll
            for (int r = 0; r < 4; r++) pm = fmaxf(pm, sacc[nb][r]);
        pm = fmaxf(pm, __shfl_xor(pm, 16));
        pm = fmaxf(pm, __shfl_xor(pm, 32));

        // defer-max: rescale only when the row max grew by > 8
        if (!__all(pm <= m_run + 8.0f)) {
            float mn = fmaxf(m_run, pm);
            float sc = __expf(m_run - mn);
            m_run = mn;
            l_run *= sc;
#pragma unroll
            for (int r = 0; r < 4; r++) {
                float s4 = __shfl(sc, g * 4 + r);   // scale of q-row (g*4+r)
#pragma unroll
                for (int db = 0; db < 8; db++) ao[db][r] *= s4;
            }
        }

        float rs = 0.f;
#pragma unroll
        for (int nb = 0; nb < 4; nb++) {
            bf16x4 pk;
#pragma unroll
            for (int r = 0; r < 4; r++) {
                float pe = __expf(sacc[nb][r] - m_run);
                rs += pe;
                pk[r] = (bf16_t)pe;
            }
            *reinterpret_cast<bf16x4*>(&Pb[w * 16 + c][nb * 16 + g * 4]) = pk;  // ds_write_b64
        }
        rs += __shfl_xor(rs, 16);
        rs += __shfl_xor(rs, 32);
        l_run += rs;

        asm volatile("s_waitcnt lgkmcnt(0)" ::: "memory");  // Pb wave-private: fence only

        // O += P V : A-frag from Pb row c, B-frag from Vt (unchanged from r1)
        bf16x8 pf[2];
#pragma unroll
        for (int kb2 = 0; kb2 < 2; kb2++)
            pf[kb2] = *reinterpret_cast<const bf16x8*>(&Pb[w * 16 + c][kb2 * 32 + g * 8]);
        __builtin_amdgcn_s_setprio(1);
#pragma unroll
        for (int db = 0; db < 8; db++)
#pragma unroll
            for (int kb2 = 0; kb2 < 2; kb2++) {
                bf16x8 vf = *reinterpret_cast<const bf16x8*>(&Vt[db * 16 + c][kb2 * 32 + g * 8]);
                ao[db] = MFMA16(pf[kb2], vf, ao[db]);
            }
        __builtin_amdgcn_s_setprio(0);
    }

    // epilogue: normalize (broadcast 1/l per row), stage in LDS, coalesced write
    float inv = 1.0f / l_run;
    __syncthreads();
    bf16_t (*Os)[136] = reinterpret_cast<bf16_t(*)[136]>(smem);   // 128 x 136 = 17408 elems
#pragma unroll
    for (int r = 0; r < 4; r++) {
        float i4 = __shfl(inv, g * 4 + r);
        int row = w * 16 + g * 4 + r;
#pragma unroll
        for (int db = 0; db < 8; db++)
            Os[row][db * 16 + c] = (bf16_t)(ao[db][r] * i4);
    }
    __syncthreads();
    const int b = bh >> 4, h = bh & 15;
#pragma unroll
    for (int i = 0; i < 4; i++) {
        int e = tid + i * 512; int row = e >> 4, col = (e & 15) * 8;
        *reinterpret_cast<uint4*>(&AO[((size_t)(b * Ss + q0 + row)) * DH + h * Dd + col]) =
            *reinterpret_cast<const uint4*>(&Os[row][col]);
    }
}

// ---------------- output projection ----------------
__global__ __launch_bounds__(256) void k_outproj(
    const bf16_t* __restrict__ A, const bf16_t* __restrict__ Wot,
    const float* __restrict__ bo, float* __restrict__ out) {
    __shared__ bf16_t As[64][72];
    __shared__ bf16_t Bs[128][72];
    const int tid = threadIdx.x;
    const int w = tid >> 6, lane = tid & 63, c = lane & 15, g = lane >> 4;
    const int m0 = blockIdx.x * 64;

    f32x4 acc[8];
#pragma unroll
    for (int i = 0; i < 8; i++) acc[i] = f32x4{0.f, 0.f, 0.f, 0.f};

    for (int kt = 0; kt < DH; kt += 64) {
        __syncthreads();
#pragma unroll
        for (int i = 0; i < 2; i++) {
            int e = tid + i * 256; int row = e >> 3, col = (e & 7) * 8;
            *reinterpret_cast<uint4*>(&As[row][col]) =
                *reinterpret_cast<const uint4*>(&A[(size_t)(m0 + row) * DH + kt + col]);
        }
#pragma unroll
        for (int i = 0; i < 4; i++) {
            int e = tid + i * 256; int row = e >> 3, col = (e & 7) * 8;
            *reinterpret_cast<uint4*>(&Bs[row][col]) =
                *reinterpret_cast<const uint4*>(&Wot[(size_t)row * DH + kt + col]);
        }
        __syncthreads();
#pragma unroll
        for (int kb = 0; kb < 2; kb++) {
            bf16x8 af = *reinterpret_cast<const bf16x8*>(&As[w * 16 + c][kb * 32 + g * 8]);
#pragma unroll
            for (int nb = 0; nb < 8; nb++) {
                bf16x8 bfr = *reinterpret_cast<const bf16x8*>(&Bs[nb * 16 + c][kb * 32 + g * 8]);
                acc[nb] = MFMA16(af, bfr, acc[nb]);
            }
        }
    }
#pragma unroll
    for (int nb = 0; nb < 8; nb++) {
        float bs = bo[nb * 16 + c];
#pragma unroll
        for (int r = 0; r < 4; r++) {
            int row = m0 + w * 16 + g * 4 + r;
            out[(size_t)row * Dd + nb * 16 + c] = acc[nb][r] + bs;
        }
    }
}

// ---------------- launcher ----------------
extern "C" void kernel_launch(void* const* d_in, const int* in_sizes, int n_in,
                              void* d_out, int out_size, void* d_ws, size_t ws_size,
                              hipStream_t stream) {
    const float* x  = (const float*)d_in[0];
    const float* Wq = (const float*)d_in[1];
    const float* bq = (const float*)d_in[2];
    const float* Wk = (const float*)d_in[3];
    const float* bk = (const float*)d_in[4];
    const float* Wv = (const float*)d_in[5];
    const float* bv = (const float*)d_in[6];
    const float* Wo = (const float*)d_in[7];
    const float* bo = (const float*)d_in[8];
    float* out = (float*)d_out;

    char* ws = (char*)d_ws;
    bf16_t* xb  = (bf16_t*)(ws);
    bf16_t* Wt  = (bf16_t*)(ws + 1048576);
    bf16_t* Wot = (bf16_t*)(ws + 2621440);
    bf16_t* Qw  = (bf16_t*)(ws + 3145728);
    bf16_t* Kw  = (bf16_t*)(ws + 3145728 + 16777216);
    bf16_t* Vw  = (bf16_t*)(ws + 3145728 + 2 * 16777216);
    bf16_t* AO  = (bf16_t*)(ws + 3145728 + 3 * 16777216);

    k_cvt_x<<<512, 256, 0, stream>>>(x, xb);
    k_transpose_bf16<<<dim3(64, 4), dim3(32, 8), 0, stream>>>(Wq, Wt,          128, 2048);
    k_transpose_bf16<<<dim3(64, 4), dim3(32, 8), 0, stream>>>(Wk, Wt + 262144, 128, 2048);
    k_transpose_bf16<<<dim3(64, 4), dim3(32, 8), 0, stream>>>(Wv, Wt + 524288, 128, 2048);
    k_transpose_bf16<<<dim3(4, 64), dim3(32, 8), 0, stream>>>(Wo, Wot,         2048, 128);
    k_qkv<<<dim3(32, 16, 3), 256, 0, stream>>>(xb, Wt, bq, bk, bv, Qw, Kw, Vw);
    k_attn<<<512, 512, 0, stream>>>(Qw, Kw, Vw, AO);
    k_outproj<<<64, 256, 0, stream>>>(AO, Wot, bo, out);
}

// Round 3
// 206.118 us; speedup vs baseline: 1.4468x; 1.0251x over previous
//
#include <hip/hip_runtime.h>
#include <cstdint>
#include <cstddef>

typedef __bf16 bf16_t;
typedef bf16_t bf16x8 __attribute__((ext_vector_type(8)));
typedef bf16_t bf16x4 __attribute__((ext_vector_type(4)));
typedef float  f32x4  __attribute__((ext_vector_type(4)));

#define MFMA16(a, b, c) __builtin_amdgcn_mfma_f32_16x16x32_bf16((a), (b), (c), 0, 0, 0)

static constexpr int Bb = 2, Ss = 2048, Hh = 16, Dd = 128, DH = 2048;
// 1/sqrt(128) * log2(e): softmax runs in the exp2 domain (native v_exp_f32)
static constexpr float QSCALE = 0.08838834764831845f * 1.4426950408889634f;

// ---------------- merged prep: x->bf16 convert + 4 weight transposes ----------------
// grid: 1536 blocks x 256 thr. blocks 0..511: cvt x. 512..1535: transpose tiles.
__global__ __launch_bounds__(256) void k_prep(
    const float* __restrict__ x,
    const float* __restrict__ Wq, const float* __restrict__ Wk,
    const float* __restrict__ Wv, const float* __restrict__ Wo,
    bf16_t* __restrict__ xb, bf16_t* __restrict__ Wt, bf16_t* __restrict__ Wot) {
    __shared__ float t[32][33];
    const int tid = threadIdx.x;
    const int bid = blockIdx.x;
    if (bid < 512) {                       // convert x: 512*256*4 = 524288 elems
        int i = (bid * 256 + tid) * 4;
        float4 v = *reinterpret_cast<const float4*>(x + i);
        bf16x4 o;
        o[0] = (bf16_t)v.x; o[1] = (bf16_t)v.y; o[2] = (bf16_t)v.z; o[3] = (bf16_t)v.w;
        *reinterpret_cast<bf16x4*>(xb + i) = o;
        return;
    }
    const int u = bid - 512, m = u >> 8, tt = u & 255;
    const float* src; bf16_t* dst; int R, C, bx, by;
    if (m < 3) { src = (m == 0) ? Wq : (m == 1) ? Wk : Wv; dst = Wt + (size_t)m * 262144;
                 R = 128;  C = 2048; bx = tt & 63, by = tt >> 6; }
    else       { src = Wo; dst = Wot;
                 R = 2048; C = 128;  bx = tt & 3,  by = tt >> 2; }
    const int tx = tid & 31, ty = tid >> 5;          // 32 x 8
    const int c0 = bx * 32, r0 = by * 32;
#pragma unroll
    for (int i = 0; i < 4; i++)
        t[ty + i * 8][tx] = src[(size_t)(r0 + ty + i * 8) * C + c0 + tx];
    __syncthreads();
#pragma unroll
    for (int i = 0; i < 4; i++)
        dst[(size_t)(c0 + ty + i * 8) * R + r0 + tx] = (bf16_t)t[tx][ty + i * 8];
}

// ---------------- QKV projection GEMM ----------------
__global__ __launch_bounds__(256) void k_qkv(
    const bf16_t* __restrict__ xb, const bf16_t* __restrict__ Wt,
    const float* __restrict__ bq, const float* __restrict__ bk, const float* __restrict__ bv,
    bf16_t* __restrict__ Qw, bf16_t* __restrict__ Kw, bf16_t* __restrict__ Vw) {
    __shared__ bf16_t smem[18432];
    bf16_t (*As)[72] = reinterpret_cast<bf16_t(*)[72]>(smem);
    bf16_t (*Bs)[72] = reinterpret_cast<bf16_t(*)[72]>(smem + 9216);

    const int tid = threadIdx.x;
    const int w = tid >> 6, lane = tid & 63, c = lane & 15, g = lane >> 4;
    const int m0 = blockIdx.x * 128, n0g = blockIdx.y * 128, z = blockIdx.z;
    const bf16_t* Wz = Wt + (size_t)z * DH * Dd;
    const int wm = w * 32;

    f32x4 acc[2][8];
#pragma unroll
    for (int a = 0; a < 2; a++)
#pragma unroll
        for (int b = 0; b < 8; b++) acc[a][b] = f32x4{0.f, 0.f, 0.f, 0.f};

    for (int kt = 0; kt < 128; kt += 64) {
        __syncthreads();
#pragma unroll
        for (int i = 0; i < 4; i++) {
            int e = tid + i * 256; int row = e >> 3, col = (e & 7) * 8;
            *reinterpret_cast<uint4*>(&As[row][col]) =
                *reinterpret_cast<const uint4*>(&xb[(size_t)(m0 + row) * 128 + kt + col]);
        }
#pragma unroll
        for (int i = 0; i < 4; i++) {
            int e = tid + i * 256; int row = e >> 3, col = (e & 7) * 8;
            *reinterpret_cast<uint4*>(&Bs[row][col]) =
                *reinterpret_cast<const uint4*>(&Wz[(size_t)(n0g + row) * 128 + kt + col]);
        }
        __syncthreads();
#pragma unroll
        for (int kb = 0; kb < 2; kb++) {
            bf16x8 af[2];
#pragma unroll
            for (int mb = 0; mb < 2; mb++)
                af[mb] = *reinterpret_cast<const bf16x8*>(&As[wm + mb * 16 + c][kb * 32 + g * 8]);
#pragma unroll
            for (int nb = 0; nb < 8; nb++) {
                bf16x8 bfr = *reinterpret_cast<const bf16x8*>(&Bs[nb * 16 + c][kb * 32 + g * 8]);
                acc[0][nb] = MFMA16(af[0], bfr, acc[0][nb]);
                acc[1][nb] = MFMA16(af[1], bfr, acc[1][nb]);
            }
        }
    }

    const float* bias = (z == 0) ? bq : (z == 1) ? bk : bv;
    const float sc = (z == 0) ? QSCALE : 1.0f;
    const int cstride = (z == 2) ? 131 : 136;
    __syncthreads();
#pragma unroll
    for (int mb = 0; mb < 2; mb++)
#pragma unroll
        for (int nb = 0; nb < 8; nb++) {
            float bs = bias[n0g + nb * 16 + c];
#pragma unroll
            for (int r = 0; r < 4; r++) {
                int row = wm + mb * 16 + g * 4 + r;
                int col = nb * 16 + c;
                smem[row * cstride + col] = (bf16_t)((acc[mb][nb][r] + bs) * sc);
            }
        }
    __syncthreads();
    const int h = blockIdx.y;
    if (z <= 1) {
        bf16_t* O = z ? Kw : Qw;
#pragma unroll
        for (int i = 0; i < 8; i++) {
            int e = tid + i * 256; int row = e >> 4, col = (e & 15) * 8;
            int sg = m0 + row, b = sg >> 11, s2 = sg & 2047;
            *reinterpret_cast<uint4*>(&O[(((size_t)(b * Hh + h)) * Ss + s2) * Dd + col]) =
                *reinterpret_cast<const uint4*>(&smem[row * 136 + col]);
        }
    } else {
        int b = m0 >> 11; int sbase = m0 & 2047;
        const unsigned short* cs16 = reinterpret_cast<const unsigned short*>(smem);
#pragma unroll
        for (int i = 0; i < 32; i++) {
            int e = tid + i * 256; int d = e >> 6, sl2 = (e & 63) * 2;
            unsigned int lo = cs16[sl2 * 131 + d], hi = cs16[(sl2 + 1) * 131 + d];
            unsigned int pk = lo | (hi << 16);
            *reinterpret_cast<unsigned int*>(
                &Vw[(((size_t)(b * Hh + h)) * Dd + d) * Ss + sbase + sl2]) = pk;
        }
    }
}

// ---------------- flash attention (swapped QK^T + T14 async prefetch) ----------------
__global__ __launch_bounds__(512, 4) void k_attn(
    const bf16_t* __restrict__ Qw, const bf16_t* __restrict__ Kw,
    const bf16_t* __restrict__ Vw, bf16_t* __restrict__ AO) {
    __shared__ bf16_t smem[27136];
    bf16_t (*Kt)[136] = reinterpret_cast<bf16_t(*)[136]>(smem);
    bf16_t (*Vt)[72]  = reinterpret_cast<bf16_t(*)[72]>(smem + 8704);
    bf16_t (*Pb)[72]  = reinterpret_cast<bf16_t(*)[72]>(smem + 17920);

    const int tid = threadIdx.x;
    const int w = tid >> 6, lane = tid & 63, c = lane & 15, g = lane >> 4;

    const int f = blockIdx.x;                      // bijective XCD swizzle (512 % 8 == 0)
    const int wid = (f & 7) * 64 + (f >> 3);
    const int bh = wid >> 4, q0 = (wid & 15) * 128;

    const bf16_t* Qb = Qw + (size_t)bh * Ss * Dd;
    const bf16_t* Kb = Kw + (size_t)bh * Ss * Dd;
    const bf16_t* Vb = Vw + (size_t)bh * Dd * Ss;

    bf16x8 qf[4];
    const int qr = q0 + w * 16 + c;
#pragma unroll
    for (int kb = 0; kb < 4; kb++)
        qf[kb] = *reinterpret_cast<const bf16x8*>(&Qb[(size_t)qr * Dd + kb * 32 + g * 8]);

    f32x4 ao[8];
#pragma unroll
    for (int i = 0; i < 8; i++) ao[i] = f32x4{0.f, 0.f, 0.f, 0.f};
    float m_run = -1e30f, l_part = 0.f;

    // fixed per-thread staging coordinates
    const int kr0 = tid >> 4, kc0 = (tid & 15) * 8;     // K rows 0..31 (+32)
    const int vr0 = tid >> 3, vc0 = (tid & 7) * 8;      // V rows 0..63 (+64)

    // prologue: tile 0
    uint4 kp0 = *reinterpret_cast<const uint4*>(&Kb[(size_t)kr0 * Dd + kc0]);
    uint4 kp1 = *reinterpret_cast<const uint4*>(&Kb[(size_t)(kr0 + 32) * Dd + kc0]);
    uint4 vp0 = *reinterpret_cast<const uint4*>(&Vb[(size_t)vr0 * Ss + vc0]);
    uint4 vp1 = *reinterpret_cast<const uint4*>(&Vb[(size_t)(vr0 + 64) * Ss + vc0]);
    *reinterpret_cast<uint4*>(&Kt[kr0][kc0])      = kp0;
    *reinterpret_cast<uint4*>(&Kt[kr0 + 32][kc0]) = kp1;
    *reinterpret_cast<uint4*>(&Vt[vr0][vc0])      = vp0;
    *reinterpret_cast<uint4*>(&Vt[vr0 + 64][vc0]) = vp1;
    __syncthreads();

    for (int t = 0; t < 32; ++t) {
        // T14: issue next tile's loads now; write to LDS after the read-barrier
        if (t < 31) {
            const int kv1 = (t + 1) * 64;
            kp0 = *reinterpret_cast<const uint4*>(&Kb[(size_t)(kv1 + kr0) * Dd + kc0]);
            kp1 = *reinterpret_cast<const uint4*>(&Kb[(size_t)(kv1 + kr0 + 32) * Dd + kc0]);
            vp0 = *reinterpret_cast<const uint4*>(&Vb[(size_t)vr0 * Ss + kv1 + vc0]);
            vp1 = *reinterpret_cast<const uint4*>(&Vb[(size_t)(vr0 + 64) * Ss + kv1 + vc0]);
        }
        __builtin_amdgcn_sched_barrier(0);   // pin load issue above compute

        // S^T = K Q^T : q = c (lane-local row), kv = nb*16 + g*4 + r
        f32x4 sacc[4];
#pragma unroll
        for (int nb = 0; nb < 4; nb++) sacc[nb] = f32x4{0.f, 0.f, 0.f, 0.f};
        __builtin_amdgcn_s_setprio(1);
#pragma unroll
        for (int kb = 0; kb < 4; kb++)
#pragma unroll
            for (int nb = 0; nb < 4; nb++) {
                bf16x8 kf = *reinterpret_cast<const bf16x8*>(&Kt[nb * 16 + c][kb * 32 + g * 8]);
                sacc[nb] = MFMA16(kf, qf[kb], sacc[nb]);
            }
        __builtin_amdgcn_s_setprio(0);

        // online softmax in exp2 domain; lane owns full q-row
        float pm = fmaxf(fmaxf(sacc[0][0], sacc[0][1]), fmaxf(sacc[0][2], sacc[0][3]));
#pragma unroll
        for (int nb = 1; nb < 4; nb++)
#pragma unroll
            for (int r = 0; r < 4; r++) pm = fmaxf(pm, sacc[nb][r]);
        pm = fmaxf(pm, __shfl_xor(pm, 16));
        pm = fmaxf(pm, __shfl_xor(pm, 32));

        if (!__all(pm <= m_run + 11.5f)) {    // defer-max (T13), log2 domain
            float mn = fmaxf(m_run, pm);
            float sc = exp2f(m_run - mn);
            m_run = mn;
            l_part *= sc;
#pragma unroll
            for (int r = 0; r < 4; r++) {
                float s4 = __shfl(sc, g * 4 + r);
#pragma unroll
                for (int db = 0; db < 8; db++) ao[db][r] *= s4;
            }
        }

        float rs = 0.f;
#pragma unroll
        for (int nb = 0; nb < 4; nb++) {
            bf16x4 pk;
#pragma unroll
            for (int r = 0; r < 4; r++) {
                float pe = exp2f(sacc[nb][r] - m_run);
                rs += pe;
                pk[r] = (bf16_t)pe;
            }
            *reinterpret_cast<bf16x4*>(&Pb[w * 16 + c][nb * 16 + g * 4]) = pk;
        }
        l_part += rs;                          // cross-lane l reduce deferred to epilogue

        asm volatile("s_waitcnt lgkmcnt(0)" ::: "memory");  // Pb wave-private

        bf16x8 pf[2];
#pragma unroll
        for (int kb2 = 0; kb2 < 2; kb2++)
            pf[kb2] = *reinterpret_cast<const bf16x8*>(&Pb[w * 16 + c][kb2 * 32 + g * 8]);
        __builtin_amdgcn_s_setprio(1);
#pragma unroll
        for (int db = 0; db < 8; db++)
#pragma unroll
            for (int kb2 = 0; kb2 < 2; kb2++) {
                bf16x8 vf = *reinterpret_cast<const bf16x8*>(&Vt[db * 16 + c][kb2 * 32 + g * 8]);
                ao[db] = MFMA16(pf[kb2], vf, ao[db]);
            }
        __builtin_amdgcn_s_setprio(0);

        __syncthreads();                       // all waves done reading Kt/Vt
        if (t < 31) {
            *reinterpret_cast<uint4*>(&Kt[kr0][kc0])      = kp0;
            *reinterpret_cast<uint4*>(&Kt[kr0 + 32][kc0]) = kp1;
            *reinterpret_cast<uint4*>(&Vt[vr0][vc0])      = vp0;
            *reinterpret_cast<uint4*>(&Vt[vr0 + 64][vc0]) = vp1;
        }
        __syncthreads();                       // next tile staged
    }

    // epilogue: reduce l across g-lanes, normalize, coalesced write
    l_part += __shfl_xor(l_part, 16);
    l_part += __shfl_xor(l_part, 32);
    float inv = 1.0f / l_part;
    bf16_t (*Os)[136] = reinterpret_cast<bf16_t(*)[136]>(smem);
#pragma unroll
    for (int r = 0; r < 4; r++) {
        float i4 = __shfl(inv, g * 4 + r);
        int row = w * 16 + g * 4 + r;
#pragma unroll
        for (int db = 0; db < 8; db++)
            Os[row][db * 16 + c] = (bf16_t)(ao[db][r] * i4);
    }
    __syncthreads();
    const int b = bh >> 4, h = bh & 15;
#pragma unroll
    for (int i = 0; i < 4; i++) {
        int e = tid + i * 512; int row = e >> 4, col = (e & 15) * 8;
        *reinterpret_cast<uint4*>(&AO[((size_t)(b * Ss + q0 + row)) * DH + h * Dd + col]) =
            *reinterpret_cast<const uint4*>(&Os[row][col]);
    }
}

// ---------------- output projection ----------------
__global__ __launch_bounds__(256) void k_outproj(
    const bf16_t* __restrict__ A, const bf16_t* __restrict__ Wot,
    const float* __restrict__ bo, float* __restrict__ out) {
    __shared__ bf16_t As[64][72];
    __shared__ bf16_t Bs[128][72];
    const int tid = threadIdx.x;
    const int w = tid >> 6, lane = tid & 63, c = lane & 15, g = lane >> 4;
    const int m0 = blockIdx.x * 64;

    f32x4 acc[8];
#pragma unroll
    for (int i = 0; i < 8; i++) acc[i] = f32x4{0.f, 0.f, 0.f, 0.f};

    for (int kt = 0; kt < DH; kt += 64) {
        __syncthreads();
#pragma unroll
        for (int i = 0; i < 2; i++) {
            int e = tid + i * 256; int row = e >> 3, col = (e & 7) * 8;
            *reinterpret_cast<uint4*>(&As[row][col]) =
                *reinterpret_cast<const uint4*>(&A[(size_t)(m0 + row) * DH + kt + col]);
        }
#pragma unroll
        for (int i = 0; i < 4; i++) {
            int e = tid + i * 256; int row = e >> 3, col = (e & 7) * 8;
            *reinterpret_cast<uint4*>(&Bs[row][col]) =
                *reinterpret_cast<const uint4*>(&Wot[(size_t)row * DH + kt + col]);
        }
        __syncthreads();
#pragma unroll
        for (int kb = 0; kb < 2; kb++) {
            bf16x8 af = *reinterpret_cast<const bf16x8*>(&As[w * 16 + c][kb * 32 + g * 8]);
#pragma unroll
            for (int nb = 0; nb < 8; nb++) {
                bf16x8 bfr = *reinterpret_cast<const bf16x8*>(&Bs[nb * 16 + c][kb * 32 + g * 8]);
                acc[nb] = MFMA16(af, bfr, acc[nb]);
            }
        }
    }
#pragma unroll
    for (int nb = 0; nb < 8; nb++) {
        float bs = bo[nb * 16 + c];
#pragma unroll
        for (int r = 0; r < 4; r++) {
            int row = m0 + w * 16 + g * 4 + r;
            out[(size_t)row * Dd + nb * 16 + c] = acc[nb][r] + bs;
        }
    }
}

// ---------------- launcher ----------------
extern "C" void kernel_launch(void* const* d_in, const int* in_sizes, int n_in,
                              void* d_out, int out_size, void* d_ws, size_t ws_size,
                              hipStream_t stream) {
    const float* x  = (const float*)d_in[0];
    const float* Wq = (const float*)d_in[1];
    const float* bq = (const float*)d_in[2];
    const float* Wk = (const float*)d_in[3];
    const float* bk = (const float*)d_in[4];
    const float* Wv = (const float*)d_in[5];
    const float* bv = (const float*)d_in[6];
    const float* Wo = (const float*)d_in[7];
    const float* bo = (const float*)d_in[8];
    float* out = (float*)d_out;

    char* ws = (char*)d_ws;
    bf16_t* xb  = (bf16_t*)(ws);
    bf16_t* Wt  = (bf16_t*)(ws + 1048576);
    bf16_t* Wot = (bf16_t*)(ws + 2621440);
    bf16_t* Qw  = (bf16_t*)(ws + 3145728);
    bf16_t* Kw  = (bf16_t*)(ws + 3145728 + 16777216);
    bf16_t* Vw  = (bf16_t*)(ws + 3145728 + 2 * 16777216);
    bf16_t* AO  = (bf16_t*)(ws + 3145728 + 3 * 16777216);

    k_prep<<<1536, 256, 0, stream>>>(x, Wq, Wk, Wv, Wo, xb, Wt, Wot);
    k_qkv<<<dim3(32, 16, 3), 256, 0, stream>>>(xb, Wt, bq, bk, bv, Qw, Kw, Vw);
    k_attn<<<512, 512, 0, stream>>>(Qw, Kw, Vw, AO);
    k_outproj<<<64, 256, 0, stream>>>(AO, Wot, bo, out);
}